// Round 8
// baseline (237.396 us; speedup 1.0000x reference)
//
#include <hip/hip_runtime.h>
#include <hip/hip_bf16.h>
#include <stdint.h>
#include <math.h>

#define TSEQ   2048
#define NBATCH 2
#define NHEAD  16
#define HDIM   64
#define CDIM   1024

// keep iff uniform(bits) < f32(0.9)  <=>  bits < 7549747*512
#define KEEP_LIMIT 3865470464u
// 0.125 (1/sqrt(64)) * log2(e): S' = S*QSC so softmax runs in exp2 domain
#define QSC 0.18033688011112042f

typedef short  bf16x8 __attribute__((ext_vector_type(8)));
typedef float  f32x4  __attribute__((ext_vector_type(4)));

// ---------------------------------------------------------------------------
// single-inst hardware ops
// ---------------------------------------------------------------------------
__device__ __forceinline__ float fast_exp2(float x) {
    float r; asm("v_exp_f32 %0, %1" : "=v"(r) : "v"(x)); return r;
}
// packed f32x2 -> bf16x2 (low = a, high = b), RNE
__device__ __forceinline__ uint32_t cvt_pk_bf16(float a, float b) {
    uint32_t r; asm("v_cvt_pk_bf16_f32 %0, %1, %2" : "=v"(r) : "v"(a), "v"(b)); return r;
}

// ---------------------------------------------------------------------------
// threefry2x32, key (0,42), 20 rounds; returns y0 ^ y1 (JAX partitionable).
// ---------------------------------------------------------------------------
__device__ __forceinline__ uint32_t rotl32(uint32_t x, int r) {
    return __builtin_amdgcn_alignbit(x, x, 32 - r);   // 1-inst rotate
}

__device__ __forceinline__ uint32_t tf2x32_xor(uint32_t x0, uint32_t x1) {
    const uint32_t ka = 0u, kb = 42u;
    const uint32_t kc = ka ^ kb ^ 0x1BD11BDAu;
    x0 += ka; x1 += kb;
#define TFR(r) { x0 += x1; x1 = rotl32(x1, r); x1 ^= x0; }
    TFR(13) TFR(15) TFR(26) TFR(6)
    x0 += kb; x1 += kc + 1u;
    TFR(17) TFR(29) TFR(16) TFR(24)
    x0 += kc; x1 += ka + 2u;
    TFR(13) TFR(15) TFR(26) TFR(6)
    x0 += ka; x1 += kb + 3u;
    TFR(17) TFR(29) TFR(16) TFR(24)
    x0 += kb; x1 += kc + 4u;
    TFR(13) TFR(15) TFR(26) TFR(6)
    x0 += kc; x1 += ka + 5u;
#undef TFR
    return x0 ^ x1;
}

__device__ __forceinline__ float bf2f(ushort u) {
    union { uint32_t i; float f; } c; c.i = ((uint32_t)u) << 16; return c.f;
}

__device__ __forceinline__ void async_copy16(void* lds, const void* g) {
    __builtin_amdgcn_global_load_lds(
        (const __attribute__((address_space(1))) unsigned int*)g,
        (__attribute__((address_space(3))) unsigned int*)lds, 16, 0, 0);
}

// ---------------------------------------------------------------------------
// x f32 -> bf16 (same layout), 8 elems/thread
// ---------------------------------------------------------------------------
__global__ __launch_bounds__(256) void cvt_bf16(
    const float* __restrict__ src, ushort* __restrict__ dst, int n)
{
    int idx = (blockIdx.x * 256 + threadIdx.x) * 8;
    if (idx >= n) return;
    float4 a = *(const float4*)(src + idx);
    float4 b = *(const float4*)(src + idx + 4);
    uint4 o;
    o.x = cvt_pk_bf16(a.x, a.y); o.y = cvt_pk_bf16(a.z, a.w);
    o.z = cvt_pk_bf16(b.x, b.y); o.w = cvt_pk_bf16(b.z, b.w);
    *(uint4*)(dst + idx) = o;
}

// ---------------------------------------------------------------------------
// w f32 [K][N] -> bf16 [N][K]  (32x32 LDS tiles)
// ---------------------------------------------------------------------------
__global__ __launch_bounds__(256) void transpose_cvt(
    const float* __restrict__ src, ushort* __restrict__ dst, int K, int N)
{
    __shared__ float t[32][33];
    const int n0 = blockIdx.x * 32, k0 = blockIdx.y * 32;
    const int i = threadIdx.x;
    {
        int k = i >> 3, n4 = (i & 7) * 4;
        float4 v = *(const float4*)(src + (size_t)(k0 + k) * N + n0 + n4);
        t[k][n4 + 0] = v.x; t[k][n4 + 1] = v.y; t[k][n4 + 2] = v.z; t[k][n4 + 3] = v.w;
    }
    __syncthreads();
    {
        int n = i >> 3, k4 = (i & 7) * 4;
        uint2 o;
        o.x = cvt_pk_bf16(t[k4 + 0][n], t[k4 + 1][n]);
        o.y = cvt_pk_bf16(t[k4 + 2][n], t[k4 + 3][n]);
        *(uint2*)(dst + (size_t)(n0 + n) * K + k0 + k4) = o;
    }
}

// ---------------------------------------------------------------------------
// bf16 MFMA GEMM: C[M][N] = A[M][K] * Bt[N][K]^T + bias
// 128x128 tile, BK=32, 256 thr = 4 waves (2x2), double-buffered LDS.
// MODE 0: C = f32 out.
// MODE 1: scatter bf16 Q (pre-scaled by QSC), K -> [B,H,T,D]; V -> [B,H,D,T].
// ---------------------------------------------------------------------------
template<int MODE>
__global__ __launch_bounds__(256) void gemm_bf16(
    const ushort* __restrict__ A, const ushort* __restrict__ Bt,
    const float* __restrict__ bias,
    ushort* __restrict__ Q, ushort* __restrict__ Kq, ushort* __restrict__ V,
    float* __restrict__ Cf, int M, int N, int K)
{
    __shared__ ushort As[2][128 * 32];
    __shared__ ushort Bs[2][128 * 32];
    const int tid = threadIdx.x, lane = tid & 63, wid = tid >> 6;
    const int l15 = lane & 15, l4 = lane >> 4;
    const int wr = wid >> 1, wc = wid & 1;
    const int bn = blockIdx.x, bm = blockIdx.y;
    const int NTK = K >> 5;

    f32x4 acc[4][4];
#pragma unroll
    for (int m = 0; m < 4; ++m)
#pragma unroll
        for (int n = 0; n < 4; ++n) acc[m][n] = (f32x4){0.f, 0.f, 0.f, 0.f};

    auto stage = [&](int p, int k0) {
#pragma unroll
        for (int j = 0; j < 2; ++j) {
            const int rbase = wid * 32 + j * 16;
            const int row = rbase + (lane >> 2);
            const ushort* src = A + (size_t)(bm * 128 + row) * K + k0 + (lane & 3) * 8;
            async_copy16(&As[p][rbase * 32], src);
        }
#pragma unroll
        for (int j = 0; j < 2; ++j) {
            const int rbase = wid * 32 + j * 16;
            const int row = rbase + (lane >> 2);
            const ushort* src = Bt + (size_t)(bn * 128 + row) * K + k0 + (lane & 3) * 8;
            async_copy16(&Bs[p][rbase * 32], src);
        }
    };
    auto compute = [&](int p) {
        bf16x8 af[4], bf[4];
#pragma unroll
        for (int m = 0; m < 4; ++m)
            af[m] = *(const bf16x8*)&As[p][(wr * 64 + m * 16 + l15) * 32 + l4 * 8];
#pragma unroll
        for (int n = 0; n < 4; ++n)
            bf[n] = *(const bf16x8*)&Bs[p][(wc * 64 + n * 16 + l15) * 32 + l4 * 8];
#pragma unroll
        for (int m = 0; m < 4; ++m)
#pragma unroll
            for (int n = 0; n < 4; ++n)
                acc[m][n] = __builtin_amdgcn_mfma_f32_16x16x32_bf16(af[m], bf[n], acc[m][n], 0, 0, 0);
    };

    stage(0, 0);
    __syncthreads();
    for (int t = 0; t < NTK; ++t) {
        const int p = t & 1;
        if (t + 1 < NTK) stage(p ^ 1, (t + 1) << 5);
        compute(p);
        __syncthreads();
    }

    const int colbase = bn * 128 + wc * 64;
    const int rowbase = bm * 128 + wr * 64;
    if (MODE == 0) {
#pragma unroll
        for (int n = 0; n < 4; ++n) {
            const int col = colbase + n * 16 + l15;
            const float bv = bias[col];
#pragma unroll
            for (int m = 0; m < 4; ++m)
#pragma unroll
                for (int r = 0; r < 4; ++r) {
                    const int row = rowbase + m * 16 + l4 * 4 + r;
                    Cf[(size_t)row * N + col] = acc[m][n][r] + bv;
                }
        }
    } else {
#pragma unroll
        for (int n = 0; n < 4; ++n) {
            const int col = colbase + n * 16 + l15;
            const int which = col >> 10, cc = col & 1023;
            const int hh = cc >> 6, dd = cc & 63;
            const float bv = bias[col];
            const float sc = (which == 0) ? QSC : 1.0f;
#pragma unroll
            for (int m = 0; m < 4; ++m) {
                float v0 = (acc[m][n][0] + bv) * sc, v1 = (acc[m][n][1] + bv) * sc;
                float v2 = (acc[m][n][2] + bv) * sc, v3 = (acc[m][n][3] + bv) * sc;
                uint32_t pk01 = cvt_pk_bf16(v0, v1), pk23 = cvt_pk_bf16(v2, v3);
                ushort vals[4] = { (ushort)pk01, (ushort)(pk01 >> 16),
                                   (ushort)pk23, (ushort)(pk23 >> 16) };
#pragma unroll
                for (int r = 0; r < 4; ++r) {
                    const int row = rowbase + m * 16 + l4 * 4 + r;
                    const int bb = row >> 11, tt = row & 2047;
                    if (which == 0)
                        Q[(((size_t)(bb * NHEAD + hh)) * TSEQ + tt) * HDIM + dd] = vals[r];
                    else if (which == 1)
                        Kq[(((size_t)(bb * NHEAD + hh)) * TSEQ + tt) * HDIM + dd] = vals[r];
                    else
                        V[(((size_t)(bb * NHEAD + hh)) * HDIM + dd) * TSEQ + tt] = vals[r];
                }
            }
        }
    }
}

// ---------------------------------------------------------------------------
// Kernel 2: causal flash attention partials, bf16 MFMA, exact threefry drop.
// Grid x: 32 = {pair 0..15} x {half 0..1}; per pass qt = pair / 31-pair.
// Partial flash pass over half the kv range -> A (unnormalized, bf16) + m,l.
// LDS 32KB: K single-buffered (staged after the post-QK^T barrier; its
// latency hides under the long threefry/softmax phase), V double-buffered,
// Ps per-wave-private. PV uses the VERIFIED 16x16x32 MFMA via Ps (the
// 16x16x16 in-register shortcut failed r7 - unverified operand layout).
// Threefry mask (pure index fn) hoisted above QK^T to overlap MFMA phase.
// ---------------------------------------------------------------------------
__global__ __launch_bounds__(256) void attn_fwd_mfma(
    const ushort* __restrict__ Qb, const ushort* __restrict__ Kb,
    const ushort* __restrict__ VbT,
    ushort* __restrict__ Ap, float* __restrict__ mp, float* __restrict__ lp)
{
    __shared__ ushort Ks[64 * 64];        // single buffer
    __shared__ ushort Vt[2][64 * 64];     // double buffer
    __shared__ ushort Ps[64 * 64];        // per-wave-private rows
    const int tid = threadIdx.x;
    const int lane = tid & 63;
    const int wid = tid >> 6;
    const int l15 = lane & 15, l4 = lane >> 4;
    const int pair = blockIdx.x >> 1, half = blockIdx.x & 1;
    const int h = blockIdx.y, b = blockIdx.z;
    const int hb = b * NHEAD + h;
    const size_t headoff = (size_t)hb * TSEQ * HDIM;
    const ushort* Qg = Qb + headoff;
    const ushort* Kg = Kb + headoff;
    const ushort* Vg = VbT + headoff;   // [D][T] rows

    auto stageK = [&](int kt) {
        const ushort* Kt = Kg + (size_t)(kt * 64) * HDIM;
#pragma unroll
        for (int c = 0; c < 2; ++c) {
            const int rbase = wid * 16 + c * 8;     // wave-uniform
            const int row = rbase + (lane >> 3);
            const ushort* srcK = Kt + row * 64 + (((lane & 7) * 8) ^ ((row & 7) << 3));
            async_copy16(&Ks[rbase * 64], srcK);
        }
    };
    auto stageV = [&](int p, int kt) {
        const ushort* Vt0 = Vg + kt * 64;
#pragma unroll
        for (int c = 0; c < 2; ++c) {
            const int rbase = wid * 16 + c * 8;     // wave-uniform
            const int row = rbase + (lane >> 3);
            const ushort* srcV = Vt0 + (size_t)row * TSEQ + (((lane & 7) * 8) ^ ((row & 7) << 3));
            async_copy16(&Vt[p][rbase * 64], srcV);
        }
    };

    const int swq = (l15 & 7) << 3;          // Ps swizzle (row = own q = l15)
    const int prow = wid * 16 + l15;

    for (int pass = 0; pass < 2; ++pass) {
        const int qt = pass ? (TSEQ / 64 - 1) - pair : pair;
        const int ntk = qt + 1;
        const int kb = half ? (ntk + 1) >> 1 : 0;
        const int ke = half ? ntk : (ntk + 1) >> 1;
        const int pidx = (hb * 32 + qt) * 2 + half;
        const int tilerow = wid * 16 + l15;
        ushort* arow = Ap + (size_t)pidx * 4096 + tilerow * 64;

        if (kb >= ke) {   // empty half (qt=0, half=1): neutral partial
#pragma unroll
            for (int dt = 0; dt < 4; ++dt) {
                ushort4 z; z.x = z.y = z.z = z.w = 0;
                *(ushort4*)&arow[dt * 16 + l4 * 4] = z;
            }
            if (l4 == 0) { mp[pidx * 64 + tilerow] = -INFINITY; lp[pidx * 64 + tilerow] = 0.f; }
            continue;
        }

        const int qglob = qt * 64 + tilerow;   // this thread's q row
        // Q fragments (B-operand: col=q=l15, k=d); Q is pre-scaled by QSC
        bf16x8 qf0, qf1;
        {
            const ushort* qrow = Qg + (size_t)qglob * HDIM;
            qf0 = *(const bf16x8*)(qrow + l4 * 8);
            qf1 = *(const bf16x8*)(qrow + 32 + l4 * 8);
        }

        f32x4 oacc[4];
#pragma unroll
        for (int i = 0; i < 4; ++i) oacc[i] = (f32x4){0.f, 0.f, 0.f, 0.f};
        float mi = -INFINITY, li = 0.f;
        const uint32_t rowbase = ((uint32_t)hb * TSEQ + (uint32_t)qglob) * TSEQ;

        stageK(kb);
        stageV(0, kb);
        __syncthreads();

        for (int kt = kb; kt < ke; ++kt) {
            const int p = (kt - kb) & 1;
            const bool pf = (kt + 1 < ke);
            if (pf) stageV(p ^ 1, kt + 1);      // V(kt+1) -> other buffer

            // ---- hoisted threefry bits (index-only -> overlaps QK^T MFMAs)
            const int kb0 = kt * 64;
            const uint32_t idx0 = rowbase + (uint32_t)kb0;
            uint32_t tfb[4][4];
#pragma unroll
            for (int ct = 0; ct < 4; ++ct) {
                const uint32_t kk = idx0 + (uint32_t)(ct * 16 + l4 * 4);
                tfb[ct][0] = tf2x32_xor(0u, kk + 0u);
                tfb[ct][1] = tf2x32_xor(0u, kk + 1u);
                tfb[ct][2] = tf2x32_xor(0u, kk + 2u);
                tfb[ct][3] = tf2x32_xor(0u, kk + 3u);
            }

            // ---- S^T = mfma(K, Q): lane holds q-row qglob, k = ct*16+l4*4+r
            f32x4 s4[4];
#pragma unroll
            for (int ct = 0; ct < 4; ++ct) {
                const int krow = ct * 16 + l15;
                const int sw = (krow & 7) << 3;
                bf16x8 kf0 = *(const bf16x8*)&Ks[krow * 64 + ((l4 * 8) ^ sw)];
                bf16x8 kf1 = *(const bf16x8*)&Ks[krow * 64 + ((l4 * 8 + 32) ^ sw)];
                f32x4 a = {0.f, 0.f, 0.f, 0.f};
                a = __builtin_amdgcn_mfma_f32_16x16x32_bf16(kf0, qf0, a, 0, 0, 0);
                a = __builtin_amdgcn_mfma_f32_16x16x32_bf16(kf1, qf1, a, 0, 0, 0);
                s4[ct] = a;
            }
            __syncthreads();                     // all waves done reading Ks
            if (pf) stageK(kt + 1);              // K(kt+1) -> Ks (hides under softmax)

            // ---- per-thread row softmax, exp2 domain
            float ev[4][4];
            if (kt == qt) {   // diagonal tile: causal mask
#pragma unroll
                for (int ct = 0; ct < 4; ++ct)
#pragma unroll
                    for (int r = 0; r < 4; ++r) {
                        const int kglob = kb0 + ct * 16 + l4 * 4 + r;
                        ev[ct][r] = (kglob <= qglob) ? s4[ct][r] : -INFINITY;
                    }
            } else {          // full tile: no mask
#pragma unroll
                for (int ct = 0; ct < 4; ++ct)
#pragma unroll
                    for (int r = 0; r < 4; ++r) ev[ct][r] = s4[ct][r];
            }
            // max tree (max3-fusable triples)
            float mx;
            {
                float t0 = fmaxf(fmaxf(ev[0][0], ev[0][1]), ev[0][2]);
                float t1 = fmaxf(fmaxf(ev[0][3], ev[1][0]), ev[1][1]);
                float t2 = fmaxf(fmaxf(ev[1][2], ev[1][3]), ev[2][0]);
                float t3 = fmaxf(fmaxf(ev[2][1], ev[2][2]), ev[2][3]);
                float t4 = fmaxf(fmaxf(ev[3][0], ev[3][1]), ev[3][2]);
                float t5 = fmaxf(fmaxf(t0, t1), ev[3][3]);
                float t6 = fmaxf(fmaxf(t2, t3), t4);
                mx = fmaxf(t5, t6);
            }
            mx = fmaxf(mx, __shfl_xor(mx, 16));
            mx = fmaxf(mx, __shfl_xor(mx, 32));

            if (__any(mx > mi)) {               // max grew somewhere: rescale
                const float mnew = fmaxf(mi, mx);
                const float alpha = fast_exp2(mi - mnew);  // ==1 where mx<=mi
                mi = mnew;
                li *= alpha;
#pragma unroll
                for (int dt = 0; dt < 4; ++dt) {
                    oacc[dt][0] *= alpha; oacc[dt][1] *= alpha;
                    oacc[dt][2] *= alpha; oacc[dt][3] *= alpha;
                }
            }
            float rs = 0.f;
#pragma unroll
            for (int ct = 0; ct < 4; ++ct)
#pragma unroll
                for (int r = 0; r < 4; ++r) {
                    ev[ct][r] = fast_exp2(ev[ct][r] - mi);
                    rs += ev[ct][r];
                }
            rs += __shfl_xor(rs, 16);
            rs += __shfl_xor(rs, 32);
            li += rs;

            // ---- dropout gate (precomputed bits) + P -> Ps (bf16 pairs)
#pragma unroll
            for (int ct = 0; ct < 4; ++ct) {
                const float p0 = (tfb[ct][0] < KEEP_LIMIT) ? ev[ct][0] : 0.f;
                const float p1 = (tfb[ct][1] < KEEP_LIMIT) ? ev[ct][1] : 0.f;
                const float p2 = (tfb[ct][2] < KEEP_LIMIT) ? ev[ct][2] : 0.f;
                const float p3 = (tfb[ct][3] < KEEP_LIMIT) ? ev[ct][3] : 0.f;
                uint2 pk;
                pk.x = cvt_pk_bf16(p0, p1);
                pk.y = cvt_pk_bf16(p2, p3);
                *(uint2*)&Ps[prow * 64 + ((ct * 16 + l4 * 4) ^ swq)] = pk;
            }

            // ---- A^T += mfma(V^T, P): A-op=V^T[d][k], B-op=P[q][k]  (K=32, verified)
            bf16x8 pf0 = *(const bf16x8*)&Ps[prow * 64 + ((l4 * 8) ^ swq)];
            bf16x8 pf1 = *(const bf16x8*)&Ps[prow * 64 + ((l4 * 8 + 32) ^ swq)];
#pragma unroll
            for (int dt = 0; dt < 4; ++dt) {
                const int drow = dt * 16 + l15;
                const int swv = (drow & 7) << 3;
                bf16x8 vf0 = *(const bf16x8*)&Vt[p][drow * 64 + ((l4 * 8) ^ swv)];
                bf16x8 vf1 = *(const bf16x8*)&Vt[p][drow * 64 + ((l4 * 8 + 32) ^ swv)];
                oacc[dt] = __builtin_amdgcn_mfma_f32_16x16x32_bf16(vf0, pf0, oacc[dt], 0, 0, 0);
                oacc[dt] = __builtin_amdgcn_mfma_f32_16x16x32_bf16(vf1, pf1, oacc[dt], 0, 0, 0);
            }
            __syncthreads();   // drains K/V glds (vmcnt0); guards Vt[p^1] reuse
        }

        // ---- partial epilogue: A (bf16, unnormalized), m, l
#pragma unroll
        for (int dt = 0; dt < 4; ++dt) {
            uint2 o;
            o.x = cvt_pk_bf16(oacc[dt][0], oacc[dt][1]);
            o.y = cvt_pk_bf16(oacc[dt][2], oacc[dt][3]);
            *(uint2*)&arow[dt * 16 + l4 * 4] = o;
        }
        if (l4 == 0) { mp[pidx * 64 + tilerow] = mi; lp[pidx * 64 + tilerow] = li; }
    }
}

// ---------------------------------------------------------------------------
// Kernel 2b: merge the two kv-half partials -> AO bf16 [B,T,C]
// ---------------------------------------------------------------------------
__global__ __launch_bounds__(256) void attn_merge(
    const ushort* __restrict__ Ap, const float* __restrict__ mp,
    const float* __restrict__ lp, ushort* __restrict__ AO)
{
    const int gidx = blockIdx.x * 16 + (threadIdx.x >> 4);   // 0..65535
    const int hb = gidx >> 11;          // b*16+h
    const int q  = gidx & 2047;
    const int qt = q >> 6, row = q & 63;
    const int sub = (threadIdx.x & 15) * 4;
    const int pidx0 = (hb * 32 + qt) * 2;
    const int pr = pidx0 * 64 + row;
    const float m0 = mp[pr], m1 = mp[pr + 64];
    const float l0 = lp[pr], l1 = lp[pr + 64];
    const float m  = fmaxf(m0, m1);
    const float w0 = fast_exp2(m0 - m), w1 = fast_exp2(m1 - m);
    const float inv = 1.0f / ((l0 * w0 + l1 * w1) * 0.9f);
    const float s0 = w0 * inv, s1 = w1 * inv;
    ushort4 a0 = *(const ushort4*)&Ap[(size_t)pidx0 * 4096 + row * 64 + sub];
    ushort4 a1 = *(const ushort4*)&Ap[(size_t)(pidx0 + 1) * 4096 + row * 64 + sub];
    const int b = hb >> 4, h = hb & 15;
    ushort* orow = AO + ((size_t)(b * TSEQ + q)) * CDIM + h * HDIM + sub;
    uint2 o;
    o.x = cvt_pk_bf16(bf2f(a0.x) * s0 + bf2f(a1.x) * s1,
                      bf2f(a0.y) * s0 + bf2f(a1.y) * s1);
    o.y = cvt_pk_bf16(bf2f(a0.z) * s0 + bf2f(a1.z) * s1,
                      bf2f(a0.w) * s0 + bf2f(a1.w) * s1);
    *(uint2*)orow = o;
}

// ---------------------------------------------------------------------------
extern "C" void kernel_launch(void* const* d_in, const int* in_sizes, int n_in,
                              void* d_out, int out_size, void* d_ws, size_t ws_size,
                              hipStream_t stream)
{
    const float* x      = (const float*)d_in[0];
    const float* w_attn = (const float*)d_in[1];
    const float* b_attn = (const float*)d_in[2];
    const float* w_proj = (const float*)d_in[3];
    const float* b_proj = (const float*)d_in[4];
    float* out = (float*)d_out;

    const size_t NH = (size_t)NBATCH * NHEAD * TSEQ * HDIM;   // 4,194,304
    ushort* Qb  = (ushort*)d_ws;
    ushort* Kb  = Qb + NH;
    ushort* VbT = Kb + NH;                  // bf16 [B,H,D,T]
    ushort* AO  = VbT + NH;                 // bf16 [B,T,C]
    ushort* xb  = AO + NH;                  // bf16 [4096][1024]
    ushort* wTa = xb + NH;                  // bf16 [3072][1024]
    ushort* wTp = wTa + (size_t)3072 * 1024;// bf16 [1024][1024]
    float*  mp  = (float*)(wTp + (size_t)1024 * 1024);  // [2048][64]
    float*  lp  = mp + (size_t)2048 * 64;               // [2048][64]

    // A partials (bf16, 2048 x 64 x 64 = 16.8MB) live in d_out until proj.
    ushort* Aparts = (ushort*)d_out;

    cvt_bf16<<<2048, 256, 0, stream>>>(x, xb, 4096 * 1024);
    transpose_cvt<<<dim3(96, 32), 256, 0, stream>>>(w_attn, wTa, 1024, 3072);
    transpose_cvt<<<dim3(32, 32), 256, 0, stream>>>(w_proj, wTp, 1024, 1024);

    gemm_bf16<1><<<dim3(24, 32), 256, 0, stream>>>(
        xb, wTa, b_attn, Qb, Kb, VbT, nullptr, 4096, 3072, 1024);

    attn_fwd_mfma<<<dim3(32, NHEAD, NBATCH), 256, 0, stream>>>(
        Qb, Kb, VbT, Aparts, mp, lp);

    attn_merge<<<4096, 256, 0, stream>>>(Aparts, mp, lp, AO);

    gemm_bf16<0><<<dim3(8, 32), 256, 0, stream>>>(
        AO, wTp, b_proj, nullptr, nullptr, nullptr, out, 4096, 1024, 1024);
}